// Round 9
// baseline (171.539 us; speedup 1.0000x reference)
//
#include <hip/hip_runtime.h>
#include <hip/hip_bf16.h>

// Problem constants
#define Dm   1024
#define Hh   16
#define HDq  64
#define DKV  512
#define HID  128
#define Bb   2
#define Ll   2048
#define Ff   32
#define NBLK 256

typedef _Float16 half8 __attribute__((ext_vector_type(8)));
typedef float f32x4 __attribute__((ext_vector_type(4)));

__device__ __forceinline__ float gelu_exact(float x) {
    return 0.5f * x * (1.0f + erff(x * 0.70710678118654752f));
}

// Grid barrier: 256 blocks, 1 block/CU guaranteed co-resident (LDS 44KB, 4 waves).
// Release: __threadfence before arrive; acquire: __threadfence after spin.
__device__ __forceinline__ void gbar(int* c) {
    __syncthreads();
    if (threadIdx.x == 0) {
        __threadfence();
        atomicAdd(c, 1);
        while (atomicAdd(c, 0) < NBLK) __builtin_amdgcn_s_sleep(8);
    }
    __syncthreads();
    __threadfence();
}

// ---------------------------------------------------------------------------
// kfused: all 5 phases with grid barriers between.
//  P0 (192 blk): w1 hidden partials + Qc partials
//  P1 ( 64 blk): w_comb finalize (redundant per block) + Wk slice -> kwh16
//  P2 (128 blk): logits MFMA + exp + den + P-weighted h accumulation
//  P3 (256 blk): hbar reduce + Wv matvec partial
//  P4 ( 64 blk): opre finalize + Wo GEMM + bias
// ---------------------------------------------------------------------------
__global__ __launch_bounds__(256) void kfused(
        const float* __restrict__ h,
        const float* __restrict__ mu, const float* __restrict__ sigma,
        const float* __restrict__ Wq, const float* __restrict__ Wk,
        const float* __restrict__ Wv, const float* __restrict__ Wo,
        const float* __restrict__ bo,
        const float* __restrict__ tw1, const float* __restrict__ tb1,
        const float* __restrict__ tw2, const float* __restrict__ tb2,
        const float* __restrict__ dw1, const float* __restrict__ db1,
        const float* __restrict__ dw2, const float* __restrict__ db2,
        int* __restrict__ counters,
        _Float16* __restrict__ kwh16, float* __restrict__ den_part,
        float* __restrict__ hid_part, float* __restrict__ qc_part,
        float* __restrict__ opre_part, float* __restrict__ hbar_part,
        float* __restrict__ out)
{
    __shared__ __align__(16) char sm[44544];
    const int bx = blockIdx.x, t = threadIdx.x;

    // ===================== P0: partials =====================
    if (bx < 192) {
        float* hl  = (float*)sm;              // [32]
        float* red = (float*)(sm + 128);      // [256]
        if (bx < 128) {
            const int b = bx >> 6, which = (bx >> 5) & 1, js = bx & 31;
            const float* w1 = which ? dw1 : tw1;
            const float* hrow = h + ((size_t)b * Ll + (Ll - 1)) * Dm + js * 32;
            if (t < 32) hl[t] = hrow[t];
            __syncthreads();
            const int col = t & 127, rg = t >> 7;
            float acc = 0.f;
#pragma unroll
            for (int p = 0; p < 16; ++p) {
                const int row = p * 2 + rg;
                acc += hl[row] * w1[(size_t)(js * 32 + row + 1) * HID + col];
            }
            red[t] = acc;
            __syncthreads();
            if (t < 128)
                hid_part[((size_t)(b * 2 + which) * 32 + js) * HID + t] = red[t] + red[t + 128];
        } else {
            const int id = bx - 128;
            const int b = id >> 5, js = id & 31;
            const float* hrow = h + ((size_t)b * Ll + (Ll - 1)) * Dm + js * 32;
            if (t < 32) hl[t] = hrow[t];
            __syncthreads();
            float4 acc = {0.f, 0.f, 0.f, 0.f};
            const float* Wq0 = Wq + (size_t)(js * 32) * Dm + t * 4;
#pragma unroll
            for (int j = 0; j < 32; ++j) {
                const float x = hl[j];
                float4 wq = *(const float4*)(Wq0 + (size_t)j * Dm);
                acc.x += x * wq.x; acc.y += x * wq.y;
                acc.z += x * wq.z; acc.w += x * wq.w;
            }
            const int col = t * 4;
            if ((col & 63) < 32) {
                const int c = (col >> 6) * 32 + (col & 31);
                *(float4*)(qc_part + ((size_t)b * 32 + js) * DKV + c) = acc;
            }
        }
    }
    gbar(counters + 0);

    // ===================== P1: w_comb + kwh =====================
    if (bx < 64) {
        float* gh  = (float*)sm;               // [128]
        float* red = (float*)(sm + 512);       // [256]
        float* wc  = (float*)(sm + 1536);      // [512]
        float (*kl)[36] = (float(*)[36])(sm + 3584);   // [16][36]
        float* scal = (float*)(sm + 5888);     // tau, sm, mm
        const int jt = bx & 31, b = bx >> 5;

        if (t == 0) {
            float s = 0.f;
            for (int f = 0; f < Ff; ++f) s += sigma[((size_t)b * Ll + (Ll - 1)) * Ff + f];
            scal[1] = fmaxf(s / (float)Ff, 1e-6f);
        }
        if (t == 64) {
            float s = 0.f;
            for (int f = 0; f < Ff; ++f) s += mu[((size_t)b * Ll + (Ll - 1)) * Ff + f];
            scal[2] = s / (float)Ff;
        }
        __syncthreads();

        if (t < 128) {
            float a = tb1[t] + scal[1] * tw1[t];
#pragma unroll
            for (int s = 0; s < 32; ++s)
                a += hid_part[((size_t)(b * 2 + 0) * 32 + s) * HID + t];
            red[t] = gelu_exact(a) * tw2[t];
        } else {
            const int hh = t - 128;
            float a = db1[hh] + scal[2] * dw1[hh];
#pragma unroll
            for (int s = 0; s < 32; ++s)
                a += hid_part[((size_t)(b * 2 + 1) * 32 + s) * HID + hh];
            gh[hh] = gelu_exact(a);
            red[t] = 0.f;
        }
        __syncthreads();
        for (int s = 128; s > 0; s >>= 1) {
            if (t < s) red[t] += red[t + s];
            __syncthreads();
        }
        if (t == 0) {
            float s = red[0] + tb2[0];
            scal[0] = expf(fminf(fmaxf(s, -3.f), 3.f));
        }
        __syncthreads();

        const int c0 = t, c1 = t + 256;
        float d0 = db2[c0], d1 = db2[c1];
#pragma unroll 16
        for (int i = 0; i < HID; ++i) {
            const float x = gh[i];
            d0 += x * dw2[(size_t)i * DKV + c0];
            d1 += x * dw2[(size_t)i * DKV + c1];
        }
        d0 = fminf(fmaxf(d0, -5.f), 5.f);
        d1 = fminf(fmaxf(d1, -5.f), 5.f);
        float q0 = 0.f, q1 = 0.f;
#pragma unroll
        for (int s = 0; s < 32; ++s) {
            const float* qp = qc_part + ((size_t)b * 32 + s) * DKV;
            q0 += qp[c0];
            q1 += qp[c1];
        }
        const float inv_sqrt = 0.17677669529663687f;
        wc[c0] = scal[0] * q0 * inv_sqrt + d0;
        wc[c1] = scal[0] * q1 * inv_sqrt + d1;
        __syncthreads();

        const float w0 = wc[t * 2], w1v = wc[t * 2 + 1];
        const int hd = t >> 4;
#pragma unroll 4
        for (int jj = 0; jj < 32; ++jj) {
            const int j = jt * 32 + jj;
            float2 kv = *(const float2*)(Wk + (size_t)j * DKV + t * 2);
            float p = kv.x * w0 + kv.y * w1v;
            p += __shfl_xor(p, 1); p += __shfl_xor(p, 2);
            p += __shfl_xor(p, 4); p += __shfl_xor(p, 8);
            if ((t & 15) == 0) kl[hd][jj] = p;
        }
        __syncthreads();
        if (t < 64) {
            const int head = t & 15, jl = (t >> 4) * 8;
            half8 v;
#pragma unroll
            for (int e = 0; e < 8; ++e) v[e] = (_Float16)kl[head][jl + e];
            *(half8*)(kwh16 + ((size_t)(b * 32 + jt)) * 512 + t * 8) = v;
        }
    }
    gbar(counters + 1);

    // ===================== P2: logits + exp + den + hbar =====================
    if (bx < 128) {
        _Float16* Kw = (_Float16*)sm;                     // 32 KB
        float (*lred)[32][17] = (float(*)[32][17])(sm + 32768);  // 8704 B
        float (*p_lds)[16] = (float(*)[16])(sm + 41472);  // 2 KB
        const int b = bx >> 6, rt = bx & 63;
        const int w = t >> 6, l = t & 63;
        const int rows0 = (b * 64 + rt) * 32;

#pragma unroll
        for (int i = 0; i < 8; ++i) {
            const int idx = i * 256 + t;
            *(half8*)(Kw + idx * 8) = *(const half8*)(kwh16 + (size_t)b * 16384 + idx * 8);
        }
        __syncthreads();

        f32x4 lacc[2] = {};
        const float* ap = h + (size_t)(rows0 + (l & 15)) * Dm + (l >> 4) * 8;
#pragma unroll
        for (int mt = 0; mt < 2; ++mt) {
            const float* apm = ap + (size_t)mt * 16 * Dm;
#pragma unroll
            for (int ks = 0; ks < 8; ++ks) {
                const int kt = w * 8 + ks;
                float4 x0 = *(const float4*)(apm + kt * 32);
                float4 x1 = *(const float4*)(apm + kt * 32 + 4);
                half8 af;
                af[0] = (_Float16)x0.x; af[1] = (_Float16)x0.y; af[2] = (_Float16)x0.z; af[3] = (_Float16)x0.w;
                af[4] = (_Float16)x1.x; af[5] = (_Float16)x1.y; af[6] = (_Float16)x1.z; af[7] = (_Float16)x1.w;
                half8 kf = *(const half8*)(Kw + kt * 512 + l * 8);
                lacc[mt] = __builtin_amdgcn_mfma_f32_16x16x32_f16(af, kf, lacc[mt], 0, 0, 0);
            }
        }
#pragma unroll
        for (int mt = 0; mt < 2; ++mt)
#pragma unroll
            for (int r = 0; r < 4; ++r)
                lred[w][mt * 16 + (l >> 4) * 4 + r][l & 15] = lacc[mt][r];
        __syncthreads();

#pragma unroll
        for (int i = 0; i < 2; ++i) {
            const int row = i * 16 + (t >> 4), head = t & 15;
            float val = lred[0][row][head] + lred[1][row][head]
                      + lred[2][row][head] + lred[3][row][head];
            val = fminf(fmaxf(val, -50.f), 50.f);
            p_lds[row][head] = __expf(val - 50.f);
        }
        __syncthreads();

        if (t < 16) {
            float s = 0.f;
#pragma unroll
            for (int r = 0; r < 32; ++r) s += p_lds[r][t];
            den_part[((size_t)b * Hh + t) * 64 + rt] = s;
        }

        const int j0 = (t & 63) * 16;
        const int h0 = (t >> 6) * 4;
        f32x4 acc2[4][4] = {};                            // [jj][hh]
#pragma unroll 8
        for (int l2 = 0; l2 < 32; ++l2) {
            const float* hr = h + (size_t)(rows0 + l2) * Dm + j0;
            f32x4 hv[4];
#pragma unroll
            for (int jj = 0; jj < 4; ++jj) hv[jj] = *(const f32x4*)(hr + jj * 4);
            f32x4 pp = *(const f32x4*)(&p_lds[l2][h0]);
#pragma unroll
            for (int hh = 0; hh < 4; ++hh)
#pragma unroll
                for (int jj = 0; jj < 4; ++jj)
                    acc2[jj][hh] += hv[jj] * pp[hh];
        }
#pragma unroll
        for (int hh = 0; hh < 4; ++hh) {
            float* dst = hbar_part + ((size_t)(b * 64 + rt) * Hh + h0 + hh) * Dm + j0;
#pragma unroll
            for (int jj = 0; jj < 4; ++jj)
                *(f32x4*)(dst + jj * 4) = acc2[jj][hh];
        }
    }
    gbar(counters + 2);

    // ===================== P3: hbar reduce + Wv partial =====================
    {
        f32x4 (*pA)[8] = (f32x4(*)[8])sm;            // [32][8]
        float* hb  = (float*)(sm + 4096);            // [128]
        float* red = (float*)(sm + 4608);            // [256]
        const int hd = bx & 15, b = (bx >> 4) & 1, js = bx >> 5;

        const int slot = t >> 3, rs = t & 7;
        f32x4 a = {};
#pragma unroll
        for (int i = 0; i < 8; ++i) {
            const int rt = rs + i * 8;
            a += *(const f32x4*)(hbar_part + ((size_t)(b * 64 + rt) * Hh + hd) * Dm + js * 128 + slot * 4);
        }
        pA[slot][rs] = a;
        __syncthreads();
        if (t < 32) {
            f32x4 s = {};
#pragma unroll
            for (int r = 0; r < 8; ++r) s += pA[t][r];
            *(f32x4*)(hb + t * 4) = s;
        }
        __syncthreads();

        const int c = t & 31, jg = t >> 5;
        float acc = 0.f;
#pragma unroll
        for (int i = 0; i < 16; ++i)
            acc += hb[jg * 16 + i] * Wv[(size_t)(js * 128 + jg * 16 + i) * DKV + hd * 32 + c];
        red[t] = acc;
        __syncthreads();
        if (t < 32) {
            float s = 0.f;
#pragma unroll
            for (int g = 0; g < 8; ++g) s += red[g * 32 + t];
            opre_part[((size_t)(b * Hh + hd) * 8 + js) * 32 + t] = s;
        }
    }
    gbar(counters + 3);

    // ===================== P4: out GEMM =====================
    if (bx < 64) {
        float* op    = (float*)sm;                   // [512]
        float* den_s = (float*)(sm + 2048);          // [16]
        float* red   = (float*)(sm + 2176);          // [256]
        const int nt = bx & 31, b = bx >> 5;

        if (t < 16) {
            float s = 0.f;
#pragma unroll 16
            for (int rt = 0; rt < 64; ++rt)
                s += den_part[((size_t)b * Hh + t) * 64 + rt];
            den_s[t] = s;
        }
        __syncthreads();
#pragma unroll
        for (int cc = 0; cc < 2; ++cc) {
            const int c = cc * 256 + t;
            float s = 0.f;
#pragma unroll
            for (int js = 0; js < 8; ++js)
                s += opre_part[((size_t)(b * Hh + (c >> 5)) * 8 + js) * 32 + (c & 31)];
            op[c] = s / den_s[c >> 5];
        }
        __syncthreads();

        const int nl = t & 31, cg = t >> 5;
        const int n = nt * 32 + nl;
        float acc = 0.f;
#pragma unroll 16
        for (int c = cg * 64; c < cg * 64 + 64; ++c)
            acc += op[c] * Wo[(size_t)c * Dm + n];
        red[t] = acc;
        __syncthreads();
        if (t < 32) {
            float s = 0.f;
#pragma unroll
            for (int g = 0; g < 8; ++g) s += red[g * 32 + t];
            out[(size_t)b * Dm + nt * 32 + t] = bo[nt * 32 + t] + s;
        }
    }
}

// ---------------------------------------------------------------------------
extern "C" void kernel_launch(void* const* d_in, const int* in_sizes, int n_in,
                              void* d_out, int out_size, void* d_ws, size_t ws_size,
                              hipStream_t stream) {
    const float* h      = (const float*)d_in[0];
    const float* mu     = (const float*)d_in[1];
    const float* sigma  = (const float*)d_in[2];
    const float* Wq     = (const float*)d_in[3];
    const float* Wk     = (const float*)d_in[4];
    const float* Wv     = (const float*)d_in[5];
    const float* Wo     = (const float*)d_in[6];
    const float* bo     = (const float*)d_in[7];
    const float* tau_w1 = (const float*)d_in[8];
    const float* tau_b1 = (const float*)d_in[9];
    const float* tau_w2 = (const float*)d_in[10];
    const float* tau_b2 = (const float*)d_in[11];
    const float* del_w1 = (const float*)d_in[12];
    const float* del_b1 = (const float*)d_in[13];
    const float* del_w2 = (const float*)d_in[14];
    const float* del_b2 = (const float*)d_in[15];
    float* out = (float*)d_out;

    // workspace layout (~8.6 MB)
    int* counters    = (int*)d_ws;                          // 16 ints (64 B)
    _Float16* kwh16  = (_Float16*)((char*)d_ws + 64);       // 32768 halfs
    float* den_part  = (float*)(kwh16 + 32768);             // 2048
    float* hid_part  = den_part + 2048;                     // 16384
    float* qc_part   = hid_part + 16384;                    // 32768
    float* opre_part = qc_part + 32768;                     // 8192
    float* hbar_part = opre_part + 8192;                    // 2M f32

    hipMemsetAsync(counters, 0, 64, stream);
    kfused<<<NBLK, 256, 0, stream>>>(h, mu, sigma, Wq, Wk, Wv, Wo, bo,
                                     tau_w1, tau_b1, tau_w2, tau_b2,
                                     del_w1, del_b1, del_w2, del_b2,
                                     counters, kwh16, den_part, hid_part,
                                     qc_part, opre_part, hbar_part, out);
}

// Round 10
// 141.169 us; speedup vs baseline: 1.2151x; 1.2151x over previous
//
#include <hip/hip_runtime.h>
#include <hip/hip_bf16.h>

// Problem constants
#define Dm   1024
#define Hh   16
#define HDq  64
#define DKV  512
#define HID  128
#define Bb   2
#define Ll   2048
#define Ff   32
#define NBLK 256

typedef _Float16 half8 __attribute__((ext_vector_type(8)));
typedef float f32x4 __attribute__((ext_vector_type(4)));

__device__ __forceinline__ float gelu_exact(float x) {
    return 0.5f * x * (1.0f + erff(x * 0.70710678118654752f));
}

// Grid barrier v2: tree arrivals (16 leaf lines + root), poll via device-scope
// relaxed atomic LOADS (no RMW ping-pong). 256 blocks, 1 block/CU co-resident.
// Counter layout: barrier k uses lines [k*17 .. k*17+16], 16 ints (64B) apart.
__device__ __forceinline__ void gbar2(int* cb, int k) {
    __syncthreads();
    if (threadIdx.x == 0) {
        __threadfence();   // release: prior writes visible device-wide
        int* leaf = cb + (k * 17 + (blockIdx.x & 15)) * 16;
        int* root = cb + (k * 17 + 16) * 16;
        if (__hip_atomic_fetch_add(leaf, 1, __ATOMIC_RELAXED,
                                   __HIP_MEMORY_SCOPE_AGENT) == 15)
            __hip_atomic_fetch_add(root, 1, __ATOMIC_RELAXED,
                                   __HIP_MEMORY_SCOPE_AGENT);
        while (__hip_atomic_load(root, __ATOMIC_RELAXED,
                                 __HIP_MEMORY_SCOPE_AGENT) < 16)
            __builtin_amdgcn_s_sleep(2);
    }
    __syncthreads();
    __threadfence();       // acquire: see producers' writes
}

// ---------------------------------------------------------------------------
// kfused: all 5 phases with tree grid barriers between.
//  P0 (192 blk): w1 hidden partials + Qc partials
//  P1 ( 64 blk): w_comb finalize (redundant per block) + Wk slice -> kwh16
//  P2 (128 blk): logits MFMA + exp + den + P-weighted h accumulation
//  P3 (256 blk): hbar reduce + Wv matvec partial
//  P4 ( 64 blk): opre finalize + Wo GEMM + bias
// ---------------------------------------------------------------------------
__global__ __launch_bounds__(256) void kfused(
        const float* __restrict__ h,
        const float* __restrict__ mu, const float* __restrict__ sigma,
        const float* __restrict__ Wq, const float* __restrict__ Wk,
        const float* __restrict__ Wv, const float* __restrict__ Wo,
        const float* __restrict__ bo,
        const float* __restrict__ tw1, const float* __restrict__ tb1,
        const float* __restrict__ tw2, const float* __restrict__ tb2,
        const float* __restrict__ dw1, const float* __restrict__ db1,
        const float* __restrict__ dw2, const float* __restrict__ db2,
        int* __restrict__ counters,
        _Float16* __restrict__ kwh16, float* __restrict__ den_part,
        float* __restrict__ hid_part, float* __restrict__ qc_part,
        float* __restrict__ opre_part, float* __restrict__ hbar_part,
        float* __restrict__ out)
{
    __shared__ __align__(16) char sm[44544];
    const int bx = blockIdx.x, t = threadIdx.x;

    // ===================== P0: partials =====================
    if (bx < 192) {
        float* hl  = (float*)sm;              // [32]
        float* red = (float*)(sm + 128);      // [256]
        if (bx < 128) {
            const int b = bx >> 6, which = (bx >> 5) & 1, js = bx & 31;
            const float* w1 = which ? dw1 : tw1;
            const float* hrow = h + ((size_t)b * Ll + (Ll - 1)) * Dm + js * 32;
            if (t < 32) hl[t] = hrow[t];
            __syncthreads();
            const int col = t & 127, rg = t >> 7;
            float acc = 0.f;
#pragma unroll
            for (int p = 0; p < 16; ++p) {
                const int row = p * 2 + rg;
                acc += hl[row] * w1[(size_t)(js * 32 + row + 1) * HID + col];
            }
            red[t] = acc;
            __syncthreads();
            if (t < 128)
                hid_part[((size_t)(b * 2 + which) * 32 + js) * HID + t] = red[t] + red[t + 128];
        } else {
            const int id = bx - 128;
            const int b = id >> 5, js = id & 31;
            const float* hrow = h + ((size_t)b * Ll + (Ll - 1)) * Dm + js * 32;
            if (t < 32) hl[t] = hrow[t];
            __syncthreads();
            float4 acc = {0.f, 0.f, 0.f, 0.f};
            const float* Wq0 = Wq + (size_t)(js * 32) * Dm + t * 4;
#pragma unroll
            for (int j = 0; j < 32; ++j) {
                const float x = hl[j];
                float4 wq = *(const float4*)(Wq0 + (size_t)j * Dm);
                acc.x += x * wq.x; acc.y += x * wq.y;
                acc.z += x * wq.z; acc.w += x * wq.w;
            }
            const int col = t * 4;
            if ((col & 63) < 32) {
                const int c = (col >> 6) * 32 + (col & 31);
                *(float4*)(qc_part + ((size_t)b * 32 + js) * DKV + c) = acc;
            }
        }
    }
    gbar2(counters, 0);

    // ===================== P1: w_comb + kwh =====================
    if (bx < 64) {
        float* gh  = (float*)sm;               // [128]
        float* red = (float*)(sm + 512);       // [256]
        float* wc  = (float*)(sm + 1536);      // [512]
        float (*kl)[36] = (float(*)[36])(sm + 3584);   // [16][36]
        float* scal = (float*)(sm + 5888);     // tau, sm, mm
        const int jt = bx & 31, b = bx >> 5;

        if (t == 0) {
            float s = 0.f;
            for (int f = 0; f < Ff; ++f) s += sigma[((size_t)b * Ll + (Ll - 1)) * Ff + f];
            scal[1] = fmaxf(s / (float)Ff, 1e-6f);
        }
        if (t == 64) {
            float s = 0.f;
            for (int f = 0; f < Ff; ++f) s += mu[((size_t)b * Ll + (Ll - 1)) * Ff + f];
            scal[2] = s / (float)Ff;
        }
        __syncthreads();

        if (t < 128) {
            float a = tb1[t] + scal[1] * tw1[t];
#pragma unroll
            for (int s = 0; s < 32; ++s)
                a += hid_part[((size_t)(b * 2 + 0) * 32 + s) * HID + t];
            red[t] = gelu_exact(a) * tw2[t];
        } else {
            const int hh = t - 128;
            float a = db1[hh] + scal[2] * dw1[hh];
#pragma unroll
            for (int s = 0; s < 32; ++s)
                a += hid_part[((size_t)(b * 2 + 1) * 32 + s) * HID + hh];
            gh[hh] = gelu_exact(a);
            red[t] = 0.f;
        }
        __syncthreads();
        for (int s = 128; s > 0; s >>= 1) {
            if (t < s) red[t] += red[t + s];
            __syncthreads();
        }
        if (t == 0) {
            float s = red[0] + tb2[0];
            scal[0] = expf(fminf(fmaxf(s, -3.f), 3.f));
        }
        __syncthreads();

        const int c0 = t, c1 = t + 256;
        float d0 = db2[c0], d1 = db2[c1];
#pragma unroll 16
        for (int i = 0; i < HID; ++i) {
            const float x = gh[i];
            d0 += x * dw2[(size_t)i * DKV + c0];
            d1 += x * dw2[(size_t)i * DKV + c1];
        }
        d0 = fminf(fmaxf(d0, -5.f), 5.f);
        d1 = fminf(fmaxf(d1, -5.f), 5.f);
        float q0 = 0.f, q1 = 0.f;
#pragma unroll
        for (int s = 0; s < 32; ++s) {
            const float* qp = qc_part + ((size_t)b * 32 + s) * DKV;
            q0 += qp[c0];
            q1 += qp[c1];
        }
        const float inv_sqrt = 0.17677669529663687f;
        wc[c0] = scal[0] * q0 * inv_sqrt + d0;
        wc[c1] = scal[0] * q1 * inv_sqrt + d1;
        __syncthreads();

        const float w0 = wc[t * 2], w1v = wc[t * 2 + 1];
        const int hd = t >> 4;
#pragma unroll 4
        for (int jj = 0; jj < 32; ++jj) {
            const int j = jt * 32 + jj;
            float2 kv = *(const float2*)(Wk + (size_t)j * DKV + t * 2);
            float p = kv.x * w0 + kv.y * w1v;
            p += __shfl_xor(p, 1); p += __shfl_xor(p, 2);
            p += __shfl_xor(p, 4); p += __shfl_xor(p, 8);
            if ((t & 15) == 0) kl[hd][jj] = p;
        }
        __syncthreads();
        if (t < 64) {
            const int head = t & 15, jl = (t >> 4) * 8;
            half8 v;
#pragma unroll
            for (int e = 0; e < 8; ++e) v[e] = (_Float16)kl[head][jl + e];
            *(half8*)(kwh16 + ((size_t)(b * 32 + jt)) * 512 + t * 8) = v;
        }
    }
    gbar2(counters, 1);

    // ===================== P2: logits + exp + den + hbar =====================
    if (bx < 128) {
        _Float16* Kw = (_Float16*)sm;                     // 32 KB
        float (*lred)[32][17] = (float(*)[32][17])(sm + 32768);  // 8704 B
        float (*p_lds)[16] = (float(*)[16])(sm + 41472);  // 2 KB
        const int b = bx >> 6, rt = bx & 63;
        const int w = t >> 6, l = t & 63;
        const int rows0 = (b * 64 + rt) * 32;

#pragma unroll
        for (int i = 0; i < 8; ++i) {
            const int idx = i * 256 + t;
            *(half8*)(Kw + idx * 8) = *(const half8*)(kwh16 + (size_t)b * 16384 + idx * 8);
        }
        __syncthreads();

        f32x4 lacc[2] = {};
        const float* ap = h + (size_t)(rows0 + (l & 15)) * Dm + (l >> 4) * 8;
#pragma unroll
        for (int mt = 0; mt < 2; ++mt) {
            const float* apm = ap + (size_t)mt * 16 * Dm;
#pragma unroll
            for (int ks = 0; ks < 8; ++ks) {
                const int kt = w * 8 + ks;
                float4 x0 = *(const float4*)(apm + kt * 32);
                float4 x1 = *(const float4*)(apm + kt * 32 + 4);
                half8 af;
                af[0] = (_Float16)x0.x; af[1] = (_Float16)x0.y; af[2] = (_Float16)x0.z; af[3] = (_Float16)x0.w;
                af[4] = (_Float16)x1.x; af[5] = (_Float16)x1.y; af[6] = (_Float16)x1.z; af[7] = (_Float16)x1.w;
                half8 kf = *(const half8*)(Kw + kt * 512 + l * 8);
                lacc[mt] = __builtin_amdgcn_mfma_f32_16x16x32_f16(af, kf, lacc[mt], 0, 0, 0);
            }
        }
#pragma unroll
        for (int mt = 0; mt < 2; ++mt)
#pragma unroll
            for (int r = 0; r < 4; ++r)
                lred[w][mt * 16 + (l >> 4) * 4 + r][l & 15] = lacc[mt][r];
        __syncthreads();

#pragma unroll
        for (int i = 0; i < 2; ++i) {
            const int row = i * 16 + (t >> 4), head = t & 15;
            float val = lred[0][row][head] + lred[1][row][head]
                      + lred[2][row][head] + lred[3][row][head];
            val = fminf(fmaxf(val, -50.f), 50.f);
            p_lds[row][head] = __expf(val - 50.f);
        }
        __syncthreads();

        if (t < 16) {
            float s = 0.f;
#pragma unroll
            for (int r = 0; r < 32; ++r) s += p_lds[r][t];
            den_part[((size_t)b * Hh + t) * 64 + rt] = s;
        }

        const int j0 = (t & 63) * 16;
        const int h0 = (t >> 6) * 4;
        f32x4 acc2[4][4] = {};                            // [jj][hh]
#pragma unroll 8
        for (int l2 = 0; l2 < 32; ++l2) {
            const float* hr = h + (size_t)(rows0 + l2) * Dm + j0;
            f32x4 hv[4];
#pragma unroll
            for (int jj = 0; jj < 4; ++jj) hv[jj] = *(const f32x4*)(hr + jj * 4);
            f32x4 pp = *(const f32x4*)(&p_lds[l2][h0]);
#pragma unroll
            for (int hh = 0; hh < 4; ++hh)
#pragma unroll
                for (int jj = 0; jj < 4; ++jj)
                    acc2[jj][hh] += hv[jj] * pp[hh];
        }
#pragma unroll
        for (int hh = 0; hh < 4; ++hh) {
            float* dst = hbar_part + ((size_t)(b * 64 + rt) * Hh + h0 + hh) * Dm + j0;
#pragma unroll
            for (int jj = 0; jj < 4; ++jj)
                *(f32x4*)(dst + jj * 4) = acc2[jj][hh];
        }
    }
    gbar2(counters, 2);

    // ===================== P3: hbar reduce + Wv partial =====================
    {
        f32x4 (*pA)[8] = (f32x4(*)[8])sm;            // [32][8]
        float* hb  = (float*)(sm + 4096);            // [128]
        float* red = (float*)(sm + 4608);            // [256]
        const int hd = bx & 15, b = (bx >> 4) & 1, js = bx >> 5;

        const int slot = t >> 3, rs = t & 7;
        f32x4 a = {};
#pragma unroll
        for (int i = 0; i < 8; ++i) {
            const int rt = rs + i * 8;
            a += *(const f32x4*)(hbar_part + ((size_t)(b * 64 + rt) * Hh + hd) * Dm + js * 128 + slot * 4);
        }
        pA[slot][rs] = a;
        __syncthreads();
        if (t < 32) {
            f32x4 s = {};
#pragma unroll
            for (int r = 0; r < 8; ++r) s += pA[t][r];
            *(f32x4*)(hb + t * 4) = s;
        }
        __syncthreads();

        const int c = t & 31, jg = t >> 5;
        float acc = 0.f;
#pragma unroll
        for (int i = 0; i < 16; ++i)
            acc += hb[jg * 16 + i] * Wv[(size_t)(js * 128 + jg * 16 + i) * DKV + hd * 32 + c];
        red[t] = acc;
        __syncthreads();
        if (t < 32) {
            float s = 0.f;
#pragma unroll
            for (int g = 0; g < 8; ++g) s += red[g * 32 + t];
            opre_part[((size_t)(b * Hh + hd) * 8 + js) * 32 + t] = s;
        }
    }
    gbar2(counters, 3);

    // ===================== P4: out GEMM =====================
    if (bx < 64) {
        float* op    = (float*)sm;                   // [512]
        float* den_s = (float*)(sm + 2048);          // [16]
        float* red   = (float*)(sm + 2176);          // [256]
        const int nt = bx & 31, b = bx >> 5;

        if (t < 16) {
            float s = 0.f;
#pragma unroll 16
            for (int rt = 0; rt < 64; ++rt)
                s += den_part[((size_t)b * Hh + t) * 64 + rt];
            den_s[t] = s;
        }
        __syncthreads();
#pragma unroll
        for (int cc = 0; cc < 2; ++cc) {
            const int c = cc * 256 + t;
            float s = 0.f;
#pragma unroll
            for (int js = 0; js < 8; ++js)
                s += opre_part[((size_t)(b * Hh + (c >> 5)) * 8 + js) * 32 + (c & 31)];
            op[c] = s / den_s[c >> 5];
        }
        __syncthreads();

        const int nl = t & 31, cg = t >> 5;
        const int n = nt * 32 + nl;
        float acc = 0.f;
#pragma unroll 16
        for (int c = cg * 64; c < cg * 64 + 64; ++c)
            acc += op[c] * Wo[(size_t)c * Dm + n];
        red[t] = acc;
        __syncthreads();
        if (t < 32) {
            float s = 0.f;
#pragma unroll
            for (int g = 0; g < 8; ++g) s += red[g * 32 + t];
            out[(size_t)b * Dm + nt * 32 + t] = bo[nt * 32 + t] + s;
        }
    }
}

// ---------------------------------------------------------------------------
extern "C" void kernel_launch(void* const* d_in, const int* in_sizes, int n_in,
                              void* d_out, int out_size, void* d_ws, size_t ws_size,
                              hipStream_t stream) {
    const float* h      = (const float*)d_in[0];
    const float* mu     = (const float*)d_in[1];
    const float* sigma  = (const float*)d_in[2];
    const float* Wq     = (const float*)d_in[3];
    const float* Wk     = (const float*)d_in[4];
    const float* Wv     = (const float*)d_in[5];
    const float* Wo     = (const float*)d_in[6];
    const float* bo     = (const float*)d_in[7];
    const float* tau_w1 = (const float*)d_in[8];
    const float* tau_b1 = (const float*)d_in[9];
    const float* tau_w2 = (const float*)d_in[10];
    const float* tau_b2 = (const float*)d_in[11];
    const float* del_w1 = (const float*)d_in[12];
    const float* del_b1 = (const float*)d_in[13];
    const float* del_w2 = (const float*)d_in[14];
    const float* del_b2 = (const float*)d_in[15];
    float* out = (float*)d_out;

    // workspace layout (~8.6 MB)
    int* counters    = (int*)d_ws;                          // 4 barriers * 17 lines * 64 B
    _Float16* kwh16  = (_Float16*)((char*)d_ws + 8192);     // 32768 halfs
    float* den_part  = (float*)(kwh16 + 32768);             // 2048
    float* hid_part  = den_part + 2048;                     // 16384
    float* qc_part   = hid_part + 16384;                    // 32768
    float* opre_part = qc_part + 32768;                     // 8192
    float* hbar_part = opre_part + 8192;                    // 2M f32

    hipMemsetAsync(counters, 0, 4352, stream);
    kfused<<<NBLK, 256, 0, stream>>>(h, mu, sigma, Wq, Wk, Wv, Wo, bo,
                                     tau_w1, tau_b1, tau_w2, tau_b2,
                                     del_w1, del_b1, del_w2, del_b2,
                                     counters, kwh16, den_part, hid_part,
                                     qc_part, opre_part, hbar_part, out);
}

// Round 12
// 56.126 us; speedup vs baseline: 3.0563x; 2.5152x over previous
//
#include <hip/hip_runtime.h>
#include <hip/hip_bf16.h>

// Problem constants
#define Dm   1024
#define Hh   16
#define HDq  64
#define DKV  512
#define HID  128
#define Bb   2
#define Ll   2048
#define Ff   32

typedef _Float16 half8 __attribute__((ext_vector_type(8)));
typedef float f32x4 __attribute__((ext_vector_type(4)));

__device__ __forceinline__ float gelu_exact(float x) {
    return 0.5f * x * (1.0f + erff(x * 0.70710678118654752f));
}

// ---------------------------------------------------------------------------
// kpart: grid 96 (b-merged: each weight row read once, used for both batches).
//   bx 0..63 : w1 hidden partials (which, js=0..31; 32 rows each) for b=0,1
//   bx 64..95: Qc partials (js=0..31; 32 rows each) for b=0,1
// ---------------------------------------------------------------------------
__global__ __launch_bounds__(256) void kpart(
        const float* __restrict__ h, const float* __restrict__ Wq,
        const float* __restrict__ tw1, const float* __restrict__ dw1,
        float* __restrict__ hid_part, float* __restrict__ qc_part)
{
    const int bx = blockIdx.x, t = threadIdx.x;
    __shared__ float hl0[32], hl1[32];
    __shared__ float red0[256], red1[256];
    if (bx < 64) {
        const int which = bx >> 5, js = bx & 31;
        const float* w1 = which ? dw1 : tw1;
        if (t < 32)       hl0[t]      = h[((size_t)0 * Ll + (Ll - 1)) * Dm + js * 32 + t];
        else if (t < 64)  hl1[t - 32] = h[((size_t)1 * Ll + (Ll - 1)) * Dm + js * 32 + (t - 32)];
        __syncthreads();
        const int col = t & 127, rg = t >> 7;
        float a0 = 0.f, a1 = 0.f;
#pragma unroll
        for (int p = 0; p < 16; ++p) {
            const int row = p * 2 + rg;
            const float w = w1[(size_t)(js * 32 + row + 1) * HID + col];
            a0 += hl0[row] * w;
            a1 += hl1[row] * w;
        }
        red0[t] = a0; red1[t] = a1;
        __syncthreads();
        if (t < 128) {
            hid_part[((size_t)(0 * 2 + which) * 32 + js) * HID + t] = red0[t] + red0[t + 128];
            hid_part[((size_t)(1 * 2 + which) * 32 + js) * HID + t] = red1[t] + red1[t + 128];
        }
    } else {
        const int js = bx - 64;
        if (t < 32)       hl0[t]      = h[((size_t)0 * Ll + (Ll - 1)) * Dm + js * 32 + t];
        else if (t < 64)  hl1[t - 32] = h[((size_t)1 * Ll + (Ll - 1)) * Dm + js * 32 + (t - 32)];
        __syncthreads();
        float4 a0 = {0.f, 0.f, 0.f, 0.f}, a1 = {0.f, 0.f, 0.f, 0.f};
        const float* Wq0 = Wq + (size_t)(js * 32) * Dm + t * 4;
#pragma unroll
        for (int j = 0; j < 32; ++j) {
            float4 wq = *(const float4*)(Wq0 + (size_t)j * Dm);
            const float x0 = hl0[j], x1 = hl1[j];
            a0.x += x0 * wq.x; a0.y += x0 * wq.y; a0.z += x0 * wq.z; a0.w += x0 * wq.w;
            a1.x += x1 * wq.x; a1.y += x1 * wq.y; a1.z += x1 * wq.z; a1.w += x1 * wq.w;
        }
        const int col = t * 4;
        if ((col & 63) < 32) {
            const int c = (col >> 6) * 32 + (col & 31);
            *(float4*)(qc_part + ((size_t)0 * 32 + js) * DKV + c) = a0;
            *(float4*)(qc_part + ((size_t)1 * 32 + js) * DKV + c) = a1;
        }
    }
}

// ---------------------------------------------------------------------------
// kkw2: grid (32 jt, Bb). Redundant w_comb finalize per block, then 32-row
// Wk slice -> fp16 MFMA B-chunk (byte-identical to R8's proven version).
// ---------------------------------------------------------------------------
__global__ __launch_bounds__(256) void kkw2(
        const float* __restrict__ mu, const float* __restrict__ sigma,
        const float* __restrict__ tw1, const float* __restrict__ tb1,
        const float* __restrict__ tw2, const float* __restrict__ tb2,
        const float* __restrict__ dw1, const float* __restrict__ db1,
        const float* __restrict__ dw2, const float* __restrict__ db2,
        const float* __restrict__ Wk,
        const float* __restrict__ hid_part, const float* __restrict__ qc_part,
        _Float16* __restrict__ kwh16)
{
    const int jt = blockIdx.x, b = blockIdx.y;
    const int t = threadIdx.x;
    __shared__ float gh[HID];
    __shared__ float red[256];
    __shared__ float wc[DKV];
    __shared__ float kl[16][36];
    __shared__ float s_tau, s_sm, s_mm;

    if (t == 0) {
        float s = 0.f;
        for (int f = 0; f < Ff; ++f) s += sigma[((size_t)b * Ll + (Ll - 1)) * Ff + f];
        s_sm = fmaxf(s / (float)Ff, 1e-6f);
    }
    if (t == 64) {
        float s = 0.f;
        for (int f = 0; f < Ff; ++f) s += mu[((size_t)b * Ll + (Ll - 1)) * Ff + f];
        s_mm = s / (float)Ff;
    }
    __syncthreads();

    if (t < 128) {
        float a = tb1[t] + s_sm * tw1[t];
#pragma unroll
        for (int s = 0; s < 32; ++s)
            a += hid_part[((size_t)(b * 2 + 0) * 32 + s) * HID + t];
        red[t] = gelu_exact(a) * tw2[t];
    } else {
        const int hh = t - 128;
        float a = db1[hh] + s_mm * dw1[hh];
#pragma unroll
        for (int s = 0; s < 32; ++s)
            a += hid_part[((size_t)(b * 2 + 1) * 32 + s) * HID + hh];
        gh[hh] = gelu_exact(a);
        red[t] = 0.f;
    }
    __syncthreads();
    for (int s = 128; s > 0; s >>= 1) {
        if (t < s) red[t] += red[t + s];
        __syncthreads();
    }
    if (t == 0) {
        float s = red[0] + tb2[0];
        s_tau = expf(fminf(fmaxf(s, -3.f), 3.f));
    }
    __syncthreads();

    const int c0 = t, c1 = t + 256;
    float d0 = db2[c0], d1 = db2[c1];
#pragma unroll 16
    for (int i = 0; i < HID; ++i) {
        const float x = gh[i];
        d0 += x * dw2[(size_t)i * DKV + c0];
        d1 += x * dw2[(size_t)i * DKV + c1];
    }
    d0 = fminf(fmaxf(d0, -5.f), 5.f);
    d1 = fminf(fmaxf(d1, -5.f), 5.f);
    float q0 = 0.f, q1 = 0.f;
#pragma unroll
    for (int s = 0; s < 32; ++s) {
        const float* qp = qc_part + ((size_t)b * 32 + s) * DKV;
        q0 += qp[c0];
        q1 += qp[c1];
    }
    const float inv_sqrt = 0.17677669529663687f;
    wc[c0] = s_tau * q0 * inv_sqrt + d0;
    wc[c1] = s_tau * q1 * inv_sqrt + d1;
    __syncthreads();

    const float w0 = wc[t * 2], w1v = wc[t * 2 + 1];
    const int hd = t >> 4;
#pragma unroll 4
    for (int jj = 0; jj < 32; ++jj) {
        const int j = jt * 32 + jj;
        float2 kv = *(const float2*)(Wk + (size_t)j * DKV + t * 2);
        float p = kv.x * w0 + kv.y * w1v;
        p += __shfl_xor(p, 1); p += __shfl_xor(p, 2);
        p += __shfl_xor(p, 4); p += __shfl_xor(p, 8);
        if ((t & 15) == 0) kl[hd][jj] = p;
    }
    __syncthreads();
    if (t < 64) {
        const int head = t & 15, jl = (t >> 4) * 8;
        half8 v;
#pragma unroll
        for (int e = 0; e < 8; ++e) v[e] = (_Float16)kl[head][jl + e];
        *(half8*)(kwh16 + ((size_t)(b * 32 + jt)) * 512 + t * 8) = v;
    }
}

// ---------------------------------------------------------------------------
// kmid: grid (128 rt, Bb) = 256 blocks (FULL GPU), 16 rows each.
//  phase 1: logits via MFMA (4-wave k-split) -> exp(val-50) -> p_lds + den_part
//  phase 2: hbar_part[(b*128+rt)][h][j] = sum_{l<16} p[l][h]*h[row0+l][j] (f32)
// ---------------------------------------------------------------------------
__global__ __launch_bounds__(256) void kmid(
        const float* __restrict__ h, const _Float16* __restrict__ kwh16,
        float* __restrict__ den_part, float* __restrict__ hbar_part)
{
    __shared__ __align__(16) _Float16 Kw[16384];      // 32 KB
    __shared__ float lred[4][16][17];
    __shared__ float p_lds[16][16];
    const int rt = blockIdx.x, b = blockIdx.y;
    const int t = threadIdx.x;
    const int w = t >> 6, l = t & 63;
    const int rows0 = (b * 128 + rt) * 16;

#pragma unroll
    for (int i = 0; i < 8; ++i) {
        const int idx = i * 256 + t;
        *(half8*)(Kw + idx * 8) = *(const half8*)(kwh16 + (size_t)b * 16384 + idx * 8);
    }
    __syncthreads();

    // phase 1: one 16-row m-tile, 4-wave k-split (8 k-steps each)
    f32x4 lacc = {};
    const float* ap = h + (size_t)(rows0 + (l & 15)) * Dm + (l >> 4) * 8;
#pragma unroll
    for (int ks = 0; ks < 8; ++ks) {
        const int kt = w * 8 + ks;
        float4 x0 = *(const float4*)(ap + kt * 32);
        float4 x1 = *(const float4*)(ap + kt * 32 + 4);
        half8 af;
        af[0] = (_Float16)x0.x; af[1] = (_Float16)x0.y; af[2] = (_Float16)x0.z; af[3] = (_Float16)x0.w;
        af[4] = (_Float16)x1.x; af[5] = (_Float16)x1.y; af[6] = (_Float16)x1.z; af[7] = (_Float16)x1.w;
        half8 kf = *(const half8*)(Kw + kt * 512 + l * 8);
        lacc = __builtin_amdgcn_mfma_f32_16x16x32_f16(af, kf, lacc, 0, 0, 0);
    }
#pragma unroll
    for (int r = 0; r < 4; ++r)
        lred[w][(l >> 4) * 4 + r][l & 15] = lacc[r];
    __syncthreads();

    {
        const int row = t >> 4, head = t & 15;        // 256 threads = 16 x 16
        float val = lred[0][row][head] + lred[1][row][head]
                  + lred[2][row][head] + lred[3][row][head];
        val = fminf(fmaxf(val, -50.f), 50.f);
        p_lds[row][head] = __expf(val - 50.f);
    }
    __syncthreads();

    if (t < 16) {
        float s = 0.f;
#pragma unroll
        for (int r = 0; r < 16; ++r) s += p_lds[r][t];
        den_part[((size_t)b * Hh + t) * 128 + rt] = s;
    }

    // phase 2: thread covers 16 j x 4 heads; h rows L2-hot from phase 1
    const int j0 = (t & 63) * 16;
    const int h0 = (t >> 6) * 4;                      // wave-uniform
    f32x4 acc2[4][4] = {};                            // [jj][hh]
#pragma unroll 4
    for (int l2 = 0; l2 < 16; ++l2) {
        const float* hr = h + (size_t)(rows0 + l2) * Dm + j0;
        f32x4 hv[4];
#pragma unroll
        for (int jj = 0; jj < 4; ++jj) hv[jj] = *(const f32x4*)(hr + jj * 4);
        f32x4 pp = *(const f32x4*)(&p_lds[l2][h0]);
#pragma unroll
        for (int hh = 0; hh < 4; ++hh)
#pragma unroll
            for (int jj = 0; jj < 4; ++jj)
                acc2[jj][hh] += hv[jj] * pp[hh];
    }
#pragma unroll
    for (int hh = 0; hh < 4; ++hh) {
        float* dst = hbar_part + ((size_t)(b * 128 + rt) * Hh + h0 + hh) * Dm + j0;
#pragma unroll
        for (int jj = 0; jj < 4; ++jj)
            *(f32x4*)(dst + jj * 4) = acc2[jj][hh];
    }
}

// ---------------------------------------------------------------------------
// kopre: grid (16 h, Bb, 8 js). Reduce 128 f32 rt-parts over its 128-j slice,
// then Wv matvec partial -> opre_part[b][h][js][32]
// ---------------------------------------------------------------------------
__global__ __launch_bounds__(256) void kopre(
        const float* __restrict__ hbar_part, const float* __restrict__ Wv,
        float* __restrict__ opre_part)
{
    const int hd = blockIdx.x, b = blockIdx.y, js = blockIdx.z;
    const int t = threadIdx.x;
    __shared__ f32x4 pA[32][8];
    __shared__ float hb[128];
    __shared__ float red[256];

    const int slot = t >> 3, rs = t & 7;              // 32 j-quads x 8 rt-lanes
    f32x4 a = {};
#pragma unroll
    for (int i = 0; i < 16; ++i) {
        const int rt = rs + i * 8;
        a += *(const f32x4*)(hbar_part + ((size_t)(b * 128 + rt) * Hh + hd) * Dm + js * 128 + slot * 4);
    }
    pA[slot][rs] = a;
    __syncthreads();
    if (t < 32) {
        f32x4 s = {};
#pragma unroll
        for (int r = 0; r < 8; ++r) s += pA[t][r];
        *(f32x4*)(hb + t * 4) = s;
    }
    __syncthreads();

    const int c = t & 31, jg = t >> 5;
    float acc = 0.f;
#pragma unroll
    for (int i = 0; i < 16; ++i)
        acc += hb[jg * 16 + i] * Wv[(size_t)(js * 128 + jg * 16 + i) * DKV + hd * 32 + c];
    red[t] = acc;
    __syncthreads();
    if (t < 32) {
        float s = 0.f;
#pragma unroll
        for (int g = 0; g < 8; ++g) s += red[g * 32 + t];
        opre_part[((size_t)(b * Hh + hd) * 8 + js) * 32 + t] = s;
    }
}

// ---------------------------------------------------------------------------
// kout: grid 32 (b-merged). Finalize den+opre for both b, then 32-n slice of
// out = opre @ Wo + bo (Wo row read once, used for both b).
// ---------------------------------------------------------------------------
__global__ __launch_bounds__(256) void kout(
        const float* __restrict__ opre_part, const float* __restrict__ den_part,
        const float* __restrict__ Wo, const float* __restrict__ bo,
        float* __restrict__ out)
{
    const int nt = blockIdx.x;
    const int t = threadIdx.x;
    __shared__ float op[2][DKV];
    __shared__ float dred[32][8];
    __shared__ float den_s[2][16];
    __shared__ float red0[256], red1[256];

    {   // den: 256 threads = 2b x 16h x 8 rt-groups
        const int b = t >> 7, hd = (t >> 3) & 15, rg = t & 7;
        float s = 0.f;
#pragma unroll
        for (int i = 0; i < 16; ++i)
            s += den_part[((size_t)b * Hh + hd) * 128 + rg + i * 8];
        dred[b * 16 + hd][rg] = s;
    }
    __syncthreads();
    if (t < 32) {
        float s = 0.f;
#pragma unroll
        for (int g = 0; g < 8; ++g) s += dred[t][g];
        den_s[t >> 4][t & 15] = s;
    }
    __syncthreads();
#pragma unroll
    for (int cc = 0; cc < 4; ++cc) {
        const int idx = cc * 256 + t;                 // 1024 = 2b x 512c
        const int b = idx >> 9, c = idx & 511;
        float s = 0.f;
#pragma unroll
        for (int js = 0; js < 8; ++js)
            s += opre_part[((size_t)(b * Hh + (c >> 5)) * 8 + js) * 32 + (c & 31)];
        op[b][c] = s / den_s[b][c >> 5];
    }
    __syncthreads();

    const int nl = t & 31, cg = t >> 5;
    const int n = nt * 32 + nl;
    float a0 = 0.f, a1 = 0.f;
#pragma unroll 16
    for (int c = cg * 64; c < cg * 64 + 64; ++c) {
        const float wv = Wo[(size_t)c * Dm + n];
        a0 += op[0][c] * wv;
        a1 += op[1][c] * wv;
    }
    red0[t] = a0; red1[t] = a1;
    __syncthreads();
    if (t < 32) {
        float s0 = 0.f, s1 = 0.f;
#pragma unroll
        for (int g = 0; g < 8; ++g) { s0 += red0[g * 32 + t]; s1 += red1[g * 32 + t]; }
        const float bv = bo[nt * 32 + t];
        out[(size_t)0 * Dm + nt * 32 + t] = bv + s0;
        out[(size_t)1 * Dm + nt * 32 + t] = bv + s1;
    }
}

// ---------------------------------------------------------------------------
extern "C" void kernel_launch(void* const* d_in, const int* in_sizes, int n_in,
                              void* d_out, int out_size, void* d_ws, size_t ws_size,
                              hipStream_t stream) {
    const float* h      = (const float*)d_in[0];
    const float* mu     = (const float*)d_in[1];
    const float* sigma  = (const float*)d_in[2];
    const float* Wq     = (const float*)d_in[3];
    const float* Wk     = (const float*)d_in[4];
    const float* Wv     = (const float*)d_in[5];
    const float* Wo     = (const float*)d_in[6];
    const float* bo     = (const float*)d_in[7];
    const float* tau_w1 = (const float*)d_in[8];
    const float* tau_b1 = (const float*)d_in[9];
    const float* tau_w2 = (const float*)d_in[10];
    const float* tau_b2 = (const float*)d_in[11];
    const float* del_w1 = (const float*)d_in[12];
    const float* del_b1 = (const float*)d_in[13];
    const float* del_w2 = (const float*)d_in[14];
    const float* del_b2 = (const float*)d_in[15];
    float* out = (float*)d_out;

    // workspace (~16.3 MB)
    _Float16* kwh16  = (_Float16*)d_ws;                     // 32768 halfs (64 KB)
    float* den_part  = (float*)(kwh16 + 32768);             // 2*16*128 = 4096
    float* hid_part  = den_part + 4096;                     // 16384
    float* qc_part   = hid_part + 16384;                    // 32768
    float* opre_part = qc_part + 32768;                     // 8192
    float* hbar_part = opre_part + 8192;                    // 256*16*1024 = 4M f32 (16 MB)

    kpart<<<96, 256, 0, stream>>>(h, Wq, tau_w1, del_w1, hid_part, qc_part);
    kkw2<<<dim3(32, Bb), 256, 0, stream>>>(mu, sigma, tau_w1, tau_b1, tau_w2, tau_b2,
                                           del_w1, del_b1, del_w2, del_b2, Wk,
                                           hid_part, qc_part, kwh16);
    kmid<<<dim3(128, Bb), 256, 0, stream>>>(h, kwh16, den_part, hbar_part);
    kopre<<<dim3(16, Bb, 8), 256, 0, stream>>>(hbar_part, Wv, opre_part);
    kout<<<32, 256, 0, stream>>>(opre_part, den_part, Wo, bo, out);
}

// Round 13
// 52.240 us; speedup vs baseline: 3.2837x; 1.0744x over previous
//
#include <hip/hip_runtime.h>
#include <hip/hip_bf16.h>

// Problem constants
#define Dm   1024
#define Hh   16
#define HDq  64
#define DKV  512
#define HID  128
#define Bb   2
#define Ll   2048
#define Ff   32

typedef _Float16 half8 __attribute__((ext_vector_type(8)));
typedef float f32x4 __attribute__((ext_vector_type(4)));

__device__ __forceinline__ float gelu_exact(float x) {
    return 0.5f * x * (1.0f + erff(x * 0.70710678118654752f));
}

// ---------------------------------------------------------------------------
// kpart: grid 96 (b-merged). Unchanged from R12 (proven).
// ---------------------------------------------------------------------------
__global__ __launch_bounds__(256) void kpart(
        const float* __restrict__ h, const float* __restrict__ Wq,
        const float* __restrict__ tw1, const float* __restrict__ dw1,
        float* __restrict__ hid_part, float* __restrict__ qc_part)
{
    const int bx = blockIdx.x, t = threadIdx.x;
    __shared__ float hl0[32], hl1[32];
    __shared__ float red0[256], red1[256];
    if (bx < 64) {
        const int which = bx >> 5, js = bx & 31;
        const float* w1 = which ? dw1 : tw1;
        if (t < 32)       hl0[t]      = h[((size_t)0 * Ll + (Ll - 1)) * Dm + js * 32 + t];
        else if (t < 64)  hl1[t - 32] = h[((size_t)1 * Ll + (Ll - 1)) * Dm + js * 32 + (t - 32)];
        __syncthreads();
        const int col = t & 127, rg = t >> 7;
        float a0 = 0.f, a1 = 0.f;
#pragma unroll
        for (int p = 0; p < 16; ++p) {
            const int row = p * 2 + rg;
            const float w = w1[(size_t)(js * 32 + row + 1) * HID + col];
            a0 += hl0[row] * w;
            a1 += hl1[row] * w;
        }
        red0[t] = a0; red1[t] = a1;
        __syncthreads();
        if (t < 128) {
            hid_part[((size_t)(0 * 2 + which) * 32 + js) * HID + t] = red0[t] + red0[t + 128];
            hid_part[((size_t)(1 * 2 + which) * 32 + js) * HID + t] = red1[t] + red1[t + 128];
        }
    } else {
        const int js = bx - 64;
        if (t < 32)       hl0[t]      = h[((size_t)0 * Ll + (Ll - 1)) * Dm + js * 32 + t];
        else if (t < 64)  hl1[t - 32] = h[((size_t)1 * Ll + (Ll - 1)) * Dm + js * 32 + (t - 32)];
        __syncthreads();
        float4 a0 = {0.f, 0.f, 0.f, 0.f}, a1 = {0.f, 0.f, 0.f, 0.f};
        const float* Wq0 = Wq + (size_t)(js * 32) * Dm + t * 4;
#pragma unroll
        for (int j = 0; j < 32; ++j) {
            float4 wq = *(const float4*)(Wq0 + (size_t)j * Dm);
            const float x0 = hl0[j], x1 = hl1[j];
            a0.x += x0 * wq.x; a0.y += x0 * wq.y; a0.z += x0 * wq.z; a0.w += x0 * wq.w;
            a1.x += x1 * wq.x; a1.y += x1 * wq.y; a1.z += x1 * wq.z; a1.w += x1 * wq.w;
        }
        const int col = t * 4;
        if ((col & 63) < 32) {
            const int c = (col >> 6) * 32 + (col & 31);
            *(float4*)(qc_part + ((size_t)0 * 32 + js) * DKV + c) = a0;
            *(float4*)(qc_part + ((size_t)1 * 32 + js) * DKV + c) = a1;
        }
    }
}

// ---------------------------------------------------------------------------
// kkw2: grid (32 jt, Bb). Unchanged from R12 (proven).
// ---------------------------------------------------------------------------
__global__ __launch_bounds__(256) void kkw2(
        const float* __restrict__ mu, const float* __restrict__ sigma,
        const float* __restrict__ tw1, const float* __restrict__ tb1,
        const float* __restrict__ tw2, const float* __restrict__ tb2,
        const float* __restrict__ dw1, const float* __restrict__ db1,
        const float* __restrict__ dw2, const float* __restrict__ db2,
        const float* __restrict__ Wk,
        const float* __restrict__ hid_part, const float* __restrict__ qc_part,
        _Float16* __restrict__ kwh16)
{
    const int jt = blockIdx.x, b = blockIdx.y;
    const int t = threadIdx.x;
    __shared__ float gh[HID];
    __shared__ float red[256];
    __shared__ float wc[DKV];
    __shared__ float kl[16][36];
    __shared__ float s_tau, s_sm, s_mm;

    if (t == 0) {
        float s = 0.f;
        for (int f = 0; f < Ff; ++f) s += sigma[((size_t)b * Ll + (Ll - 1)) * Ff + f];
        s_sm = fmaxf(s / (float)Ff, 1e-6f);
    }
    if (t == 64) {
        float s = 0.f;
        for (int f = 0; f < Ff; ++f) s += mu[((size_t)b * Ll + (Ll - 1)) * Ff + f];
        s_mm = s / (float)Ff;
    }
    __syncthreads();

    if (t < 128) {
        float a = tb1[t] + s_sm * tw1[t];
#pragma unroll
        for (int s = 0; s < 32; ++s)
            a += hid_part[((size_t)(b * 2 + 0) * 32 + s) * HID + t];
        red[t] = gelu_exact(a) * tw2[t];
    } else {
        const int hh = t - 128;
        float a = db1[hh] + s_mm * dw1[hh];
#pragma unroll
        for (int s = 0; s < 32; ++s)
            a += hid_part[((size_t)(b * 2 + 1) * 32 + s) * HID + hh];
        gh[hh] = gelu_exact(a);
        red[t] = 0.f;
    }
    __syncthreads();
    for (int s = 128; s > 0; s >>= 1) {
        if (t < s) red[t] += red[t + s];
        __syncthreads();
    }
    if (t == 0) {
        float s = red[0] + tb2[0];
        s_tau = expf(fminf(fmaxf(s, -3.f), 3.f));
    }
    __syncthreads();

    const int c0 = t, c1 = t + 256;
    float d0 = db2[c0], d1 = db2[c1];
#pragma unroll 16
    for (int i = 0; i < HID; ++i) {
        const float x = gh[i];
        d0 += x * dw2[(size_t)i * DKV + c0];
        d1 += x * dw2[(size_t)i * DKV + c1];
    }
    d0 = fminf(fmaxf(d0, -5.f), 5.f);
    d1 = fminf(fmaxf(d1, -5.f), 5.f);
    float q0 = 0.f, q1 = 0.f;
#pragma unroll
    for (int s = 0; s < 32; ++s) {
        const float* qp = qc_part + ((size_t)b * 32 + s) * DKV;
        q0 += qp[c0];
        q1 += qp[c1];
    }
    const float inv_sqrt = 0.17677669529663687f;
    wc[c0] = s_tau * q0 * inv_sqrt + d0;
    wc[c1] = s_tau * q1 * inv_sqrt + d1;
    __syncthreads();

    const float w0 = wc[t * 2], w1v = wc[t * 2 + 1];
    const int hd = t >> 4;
#pragma unroll 4
    for (int jj = 0; jj < 32; ++jj) {
        const int j = jt * 32 + jj;
        float2 kv = *(const float2*)(Wk + (size_t)j * DKV + t * 2);
        float p = kv.x * w0 + kv.y * w1v;
        p += __shfl_xor(p, 1); p += __shfl_xor(p, 2);
        p += __shfl_xor(p, 4); p += __shfl_xor(p, 8);
        if ((t & 15) == 0) kl[hd][jj] = p;
    }
    __syncthreads();
    if (t < 64) {
        const int head = t & 15, jl = (t >> 4) * 8;
        half8 v;
#pragma unroll
        for (int e = 0; e < 8; ++e) v[e] = (_Float16)kl[head][jl + e];
        *(half8*)(kwh16 + ((size_t)(b * 32 + jt)) * 512 + t * 8) = v;
    }
}

// ---------------------------------------------------------------------------
// kmid: grid (128 = 64 rt x 2 jhalf, Bb) = 256 blocks, 32 rows per rt tile.
//  phase 1 (redundant per jhalf): logits via MFMA -> exp(val-50) -> p_lds;
//           den_part written by jhalf==0 only.
//  phase 2: hbar_part[(b*64+rt)][h][jh*512 .. +512] = sum_l p[l][h]*h[row0+l][j]
// ---------------------------------------------------------------------------
__global__ __launch_bounds__(256) void kmid(
        const float* __restrict__ h, const _Float16* __restrict__ kwh16,
        float* __restrict__ den_part, float* __restrict__ hbar_part)
{
    __shared__ __align__(16) _Float16 Kw[16384];      // 32 KB
    __shared__ float lred[4][32][17];                 // 8.7 KB
    __shared__ float p_lds[32][16];
    const int bx = blockIdx.x, b = blockIdx.y;
    const int rt = bx >> 1, jh = bx & 1;
    const int t = threadIdx.x;
    const int w = t >> 6, l = t & 63;
    const int rows0 = (b * 64 + rt) * 32;

#pragma unroll
    for (int i = 0; i < 8; ++i) {
        const int idx = i * 256 + t;
        *(half8*)(Kw + idx * 8) = *(const half8*)(kwh16 + (size_t)b * 16384 + idx * 8);
    }
    __syncthreads();

    // phase 1: 2 m-tiles x 8 k-steps per wave (4-wave k-split)
    f32x4 lacc[2] = {};
    const float* ap = h + (size_t)(rows0 + (l & 15)) * Dm + (l >> 4) * 8;
#pragma unroll
    for (int mt = 0; mt < 2; ++mt) {
        const float* apm = ap + (size_t)mt * 16 * Dm;
#pragma unroll
        for (int ks = 0; ks < 8; ++ks) {
            const int kt = w * 8 + ks;
            float4 x0 = *(const float4*)(apm + kt * 32);
            float4 x1 = *(const float4*)(apm + kt * 32 + 4);
            half8 af;
            af[0] = (_Float16)x0.x; af[1] = (_Float16)x0.y; af[2] = (_Float16)x0.z; af[3] = (_Float16)x0.w;
            af[4] = (_Float16)x1.x; af[5] = (_Float16)x1.y; af[6] = (_Float16)x1.z; af[7] = (_Float16)x1.w;
            half8 kf = *(const half8*)(Kw + kt * 512 + l * 8);
            lacc[mt] = __builtin_amdgcn_mfma_f32_16x16x32_f16(af, kf, lacc[mt], 0, 0, 0);
        }
    }
#pragma unroll
    for (int mt = 0; mt < 2; ++mt)
#pragma unroll
        for (int r = 0; r < 4; ++r)
            lred[w][mt * 16 + (l >> 4) * 4 + r][l & 15] = lacc[mt][r];
    __syncthreads();

#pragma unroll
    for (int i = 0; i < 2; ++i) {
        const int row = i * 16 + (t >> 4), head = t & 15;
        float val = lred[0][row][head] + lred[1][row][head]
                  + lred[2][row][head] + lred[3][row][head];
        val = fminf(fmaxf(val, -50.f), 50.f);
        p_lds[row][head] = __expf(val - 50.f);
    }
    __syncthreads();

    if (jh == 0 && t < 16) {
        float s = 0.f;
#pragma unroll
        for (int r = 0; r < 32; ++r) s += p_lds[r][t];
        den_part[((size_t)b * Hh + t) * 64 + rt] = s;
    }

    // phase 2: this block's 512-j slice; thread covers 8 j x 4 heads
    const int j0 = jh * 512 + (t & 63) * 8;
    const int h0 = (t >> 6) * 4;                      // wave-uniform
    f32x4 acc2[2][4] = {};                            // [j-quad][hh]
#pragma unroll 4
    for (int l2 = 0; l2 < 32; ++l2) {
        const float* hr = h + (size_t)(rows0 + l2) * Dm + j0;
        f32x4 hv0 = *(const f32x4*)hr;
        f32x4 hv1 = *(const f32x4*)(hr + 4);
        f32x4 pp = *(const f32x4*)(&p_lds[l2][h0]);
#pragma unroll
        for (int hh = 0; hh < 4; ++hh) {
            acc2[0][hh] += hv0 * pp[hh];
            acc2[1][hh] += hv1 * pp[hh];
        }
    }
#pragma unroll
    for (int hh = 0; hh < 4; ++hh) {
        float* dst = hbar_part + ((size_t)(b * 64 + rt) * Hh + h0 + hh) * Dm + j0;
        *(f32x4*)dst = acc2[0][hh];
        *(f32x4*)(dst + 4) = acc2[1][hh];
    }
}

// ---------------------------------------------------------------------------
// kopre: grid (16 h, Bb, 8 js). R8-verbatim geometry (64 rt parts).
// ---------------------------------------------------------------------------
__global__ __launch_bounds__(256) void kopre(
        const float* __restrict__ hbar_part, const float* __restrict__ Wv,
        float* __restrict__ opre_part)
{
    const int hd = blockIdx.x, b = blockIdx.y, js = blockIdx.z;
    const int t = threadIdx.x;
    __shared__ f32x4 pA[32][8];
    __shared__ float hb[128];
    __shared__ float red[256];

    const int slot = t >> 3, rs = t & 7;
    f32x4 a = {};
#pragma unroll
    for (int i = 0; i < 8; ++i) {
        const int rt = rs + i * 8;
        a += *(const f32x4*)(hbar_part + ((size_t)(b * 64 + rt) * Hh + hd) * Dm + js * 128 + slot * 4);
    }
    pA[slot][rs] = a;
    __syncthreads();
    if (t < 32) {
        f32x4 s = {};
#pragma unroll
        for (int r = 0; r < 8; ++r) s += pA[t][r];
        *(f32x4*)(hb + t * 4) = s;
    }
    __syncthreads();

    const int c = t & 31, jg = t >> 5;
    float acc = 0.f;
#pragma unroll
    for (int i = 0; i < 16; ++i)
        acc += hb[jg * 16 + i] * Wv[(size_t)(js * 128 + jg * 16 + i) * DKV + hd * 32 + c];
    red[t] = acc;
    __syncthreads();
    if (t < 32) {
        float s = 0.f;
#pragma unroll
        for (int g = 0; g < 8; ++g) s += red[g * 32 + t];
        opre_part[((size_t)(b * Hh + hd) * 8 + js) * 32 + t] = s;
    }
}

// ---------------------------------------------------------------------------
// kout: grid 64 (b-merged, 16 n-cols each). Finalize den+opre for both b,
// then out = opre @ Wo + bo (Wo element read once, used for both b).
// ---------------------------------------------------------------------------
__global__ __launch_bounds__(256) void kout(
        const float* __restrict__ opre_part, const float* __restrict__ den_part,
        const float* __restrict__ Wo, const float* __restrict__ bo,
        float* __restrict__ out)
{
    const int nt = blockIdx.x;
    const int t = threadIdx.x;
    __shared__ float op[2][DKV];
    __shared__ float dred[32][8];
    __shared__ float den_s[2][16];
    __shared__ float red0[256], red1[256];

    {   // den: 256 threads = 2b x 16h x 8 rt-groups over 64 rt
        const int b = t >> 7, hd = (t >> 3) & 15, rg = t & 7;
        float s = 0.f;
#pragma unroll
        for (int i = 0; i < 8; ++i)
            s += den_part[((size_t)b * Hh + hd) * 64 + rg + i * 8];
        dred[b * 16 + hd][rg] = s;
    }
    __syncthreads();
    if (t < 32) {
        float s = 0.f;
#pragma unroll
        for (int g = 0; g < 8; ++g) s += dred[t][g];
        den_s[t >> 4][t & 15] = s;
    }
    __syncthreads();
#pragma unroll
    for (int cc = 0; cc < 4; ++cc) {
        const int idx = cc * 256 + t;                 // 1024 = 2b x 512c
        const int b = idx >> 9, c = idx & 511;
        float s = 0.f;
#pragma unroll
        for (int js = 0; js < 8; ++js)
            s += opre_part[((size_t)(b * Hh + (c >> 5)) * 8 + js) * 32 + (c & 31)];
        op[b][c] = s / den_s[b][c >> 5];
    }
    __syncthreads();

    const int nl = t & 15, cg = t >> 4;               // 16 c-groups of 32
    const int n = nt * 16 + nl;
    float a0 = 0.f, a1 = 0.f;
#pragma unroll 8
    for (int c = cg * 32; c < cg * 32 + 32; ++c) {
        const float wv = Wo[(size_t)c * Dm + n];
        a0 += op[0][c] * wv;
        a1 += op[1][c] * wv;
    }
    red0[t] = a0; red1[t] = a1;
    __syncthreads();
    if (t < 16) {
        float s0 = 0.f, s1 = 0.f;
#pragma unroll
        for (int g = 0; g < 16; ++g) { s0 += red0[g * 16 + t]; s1 += red1[g * 16 + t]; }
        const float bv = bo[nt * 16 + t];
        out[(size_t)0 * Dm + nt * 16 + t] = bv + s0;
        out[(size_t)1 * Dm + nt * 16 + t] = bv + s1;
    }
}

// ---------------------------------------------------------------------------
extern "C" void kernel_launch(void* const* d_in, const int* in_sizes, int n_in,
                              void* d_out, int out_size, void* d_ws, size_t ws_size,
                              hipStream_t stream) {
    const float* h      = (const float*)d_in[0];
    const float* mu     = (const float*)d_in[1];
    const float* sigma  = (const float*)d_in[2];
    const float* Wq     = (const float*)d_in[3];
    const float* Wk     = (const float*)d_in[4];
    const float* Wv     = (const float*)d_in[5];
    const float* Wo     = (const float*)d_in[6];
    const float* bo     = (const float*)d_in[7];
    const float* tau_w1 = (const float*)d_in[8];
    const float* tau_b1 = (const float*)d_in[9];
    const float* tau_w2 = (const float*)d_in[10];
    const float* tau_b2 = (const float*)d_in[11];
    const float* del_w1 = (const float*)d_in[12];
    const float* del_b1 = (const float*)d_in[13];
    const float* del_w2 = (const float*)d_in[14];
    const float* del_b2 = (const float*)d_in[15];
    float* out = (float*)d_out;

    // workspace (~8.3 MB)
    _Float16* kwh16  = (_Float16*)d_ws;                     // 32768 halfs (64 KB)
    float* den_part  = (float*)(kwh16 + 32768);             // 2*16*64 = 2048
    float* hid_part  = den_part + 2048;                     // 16384
    float* qc_part   = hid_part + 16384;                    // 32768
    float* opre_part = qc_part + 32768;                     // 8192
    float* hbar_part = opre_part + 8192;                    // 128*16*1024 = 2M f32 (8 MB)

    kpart<<<96, 256, 0, stream>>>(h, Wq, tau_w1, del_w1, hid_part, qc_part);
    kkw2<<<dim3(32, Bb), 256, 0, stream>>>(mu, sigma, tau_w1, tau_b1, tau_w2, tau_b2,
                                           del_w1, del_b1, del_w2, del_b2, Wk,
                                           hid_part, qc_part, kwh16);
    kmid<<<dim3(128, Bb), 256, 0, stream>>>(h, kwh16, den_part, hbar_part);
    kopre<<<dim3(16, Bb, 8), 256, 0, stream>>>(hbar_part, Wv, opre_part);
    kout<<<64, 256, 0, stream>>>(opre_part, den_part, Wo, bo, out);
}